// Round 3
// baseline (3025.938 us; speedup 1.0000x reference)
//
#include <hip/hip_runtime.h>
#include <stdint.h>

typedef unsigned long long u64;

#define BATCH 16384
#define IND   768
#define HID   4096
#define NOUT  10
#define EPS   1e-5f

// ---------------------------------------------------------------------------
// Pack sign bits: bit=1  <=>  value < 0.  One wave per row, ballot per 64 cols.
// ---------------------------------------------------------------------------
__global__ void pack_sign_kernel(const float* __restrict__ src, int ld, int nwords,
                                 int nrows, u64* __restrict__ dst) {
    int gt   = blockIdx.x * blockDim.x + threadIdx.x;
    int wave = gt >> 6;
    int lane = gt & 63;
    if (wave >= nrows) return;
    const float* row = src + (size_t)wave * ld;
    u64* drow = dst + (size_t)wave * nwords;
    for (int w = 0; w < nwords; ++w) {
        float v = row[(w << 6) + lane];
        u64 m = __ballot(v < 0.0f);
        if (lane == 0) drow[w] = m;
    }
}

// ---------------------------------------------------------------------------
// Binarized GEMM (M=16384, N=4096) + bias + BN(eval) + sign -> packed output.
// C[m,n] = kfull - 2*popc(A[m,:] ^ W[n,:])
// Block tile 128x128, 256 threads, 8x8 acc/thread, 2 K-words per inner round.
// launch_bounds(256,3): LDS already caps occupancy at 3 blocks/CU, so give the
// register allocator room — keeps acc in arch VGPRs (no v_accvgpr churn).
// LDS layouts (all reads 16B-aligned uint4, <=2-way bank conflicts = free):
//   As column-major: As[kw][row], row-stride STRA=130 (u64)
//   Bs row-major:    Bs[row][kw], row-stride STRB=KC+2 (even)
// ---------------------------------------------------------------------------
template <int KC>
__global__ __launch_bounds__(256, 3) void bgemm_bn_sign(
    const u64* __restrict__ Ap, int kwA,   // A packed [M][kwA]
    const u64* __restrict__ Wp,            // W packed [4096][kwA]
    int kfull,
    const float* __restrict__ bias, const float* __restrict__ gam,
    const float* __restrict__ bet,  const float* __restrict__ mu,
    const float* __restrict__ var,
    u64* __restrict__ Op)                  // out packed [M][64]
{
    constexpr int STRA = 130;              // 128 rows + 2 pad (even, 16B align)
    constexpr int STRB = KC + 2;           // even -> 16B align for kw pairs
    __shared__ __align__(16) u64 As[KC * STRA];
    __shared__ __align__(16) u64 Bs[128 * STRB];
    __shared__ unsigned char smask[128 * 128];

    const int tid = threadIdx.x;
    const int bm  = blockIdx.x >> 5;       // 128 row blocks
    const int bn  = blockIdx.x & 31;       // 32 col blocks
    const int m0  = bm << 7;
    const int n0  = bn << 7;

    const int tn  = tid & 15;
    const int tg  = tid >> 4;              // row group 0..15
    const int rm0 = tg << 3;

    unsigned acc[8][8];
    #pragma unroll
    for (int i = 0; i < 8; ++i)
        #pragma unroll
        for (int j = 0; j < 8; ++j) acc[i][j] = 0u;

    const int nchunks = kwA / KC;
    for (int c = 0; c < nchunks; ++c) {
        const int k0 = c * KC;
        // stage: each thread moves (128*KC)/(256*2) ulonglong2 per array
        #pragma unroll
        for (int it = 0; it < (128 * KC) / 512; ++it) {
            int idx = tid + it * 256;               // u64-pair index
            int r   = idx / (KC / 2);
            int w2  = (idx - r * (KC / 2)) * 2;
            ulonglong2 va = *(const ulonglong2*)&Ap[(size_t)(m0 + r) * kwA + k0 + w2];
            As[w2 * STRA + r]       = va.x;
            As[(w2 + 1) * STRA + r] = va.y;
            ulonglong2 vb = *(const ulonglong2*)&Wp[(size_t)(n0 + r) * kwA + k0 + w2];
            *(ulonglong2*)&Bs[r * STRB + w2] = vb;
        }
        __syncthreads();

        for (int kw = 0; kw < KC; kw += 2) {
            // A fragments for kw and kw+1, 8 rows each, as explicit u32
            unsigned a0lo[8], a0hi[8], a1lo[8], a1hi[8];
            #pragma unroll
            for (int p = 0; p < 4; ++p) {
                uint4 t0 = *(const uint4*)&As[kw * STRA + rm0 + 2 * p];
                a0lo[2 * p]     = t0.x; a0hi[2 * p]     = t0.y;
                a0lo[2 * p + 1] = t0.z; a0hi[2 * p + 1] = t0.w;
                uint4 t1 = *(const uint4*)&As[(kw + 1) * STRA + rm0 + 2 * p];
                a1lo[2 * p]     = t1.x; a1hi[2 * p]     = t1.y;
                a1lo[2 * p + 1] = t1.z; a1hi[2 * p + 1] = t1.w;
            }
            #pragma unroll
            for (int j = 0; j < 8; ++j) {
                uint4 bb = *(const uint4*)&Bs[(tn + (j << 4)) * STRB + kw];
                #pragma unroll
                for (int i = 0; i < 8; ++i) {
                    unsigned s = acc[i][j];
                    s = __popc(a0lo[i] ^ bb.x) + s;   // folds into v_bcnt acc
                    s = __popc(a0hi[i] ^ bb.y) + s;
                    s = __popc(a1lo[i] ^ bb.z) + s;
                    s = __popc(a1hi[i] ^ bb.w) + s;
                    acc[i][j] = s;
                }
            }
        }
        __syncthreads();
    }

    // epilogue: BN sign bits into LDS byte mask
    #pragma unroll
    for (int j = 0; j < 8; ++j) {
        int n = n0 + tn + (j << 4);
        float sc = gam[n] * rsqrtf(var[n] + EPS);
        float bj = bias[n], mj = mu[n], ej = bet[n];
        #pragma unroll
        for (int i = 0; i < 8; ++i) {
            float h = (float)(kfull - 2 * (int)acc[i][j]) + bj;
            float y = (h - mj) * sc + ej;
            smask[((rm0 + i) << 7) + tn + (j << 4)] = (y < 0.0f) ? 1 : 0;
        }
    }
    __syncthreads();

    // pack 64 sign bytes -> one u64 per (row, half); 256 threads = 128 rows x 2
    {
        int r = tid >> 1, h = tid & 1;
        const u64* q = (const u64*)&smask[(r << 7) + (h << 6)];
        u64 word = 0;
        #pragma unroll
        for (int t = 0; t < 8; ++t) {
            u64 bits8 = (q[t] * 0x0102040810204080ULL) >> 56;  // byte k -> bit k
            word |= bits8 << (t << 3);
        }
        Op[(size_t)(m0 + r) * 64 + (n0 >> 6) + h] = word;
    }
}

// ---------------------------------------------------------------------------
// Final layer: N=10, K=4096 words=64. One wave per row; wave-reduce 10 dots,
// BN, log_softmax, write 10 outputs.
// ---------------------------------------------------------------------------
__global__ void final_layer_kernel(
    const u64* __restrict__ Ap,   // [B][64]
    const u64* __restrict__ Wp,   // [10][64]
    const float* __restrict__ bias, const float* __restrict__ gam,
    const float* __restrict__ bet,  const float* __restrict__ mu,
    const float* __restrict__ var,
    float* __restrict__ out)      // [B][10]
{
    int gt   = blockIdx.x * blockDim.x + threadIdx.x;
    int row  = gt >> 6;
    int lane = gt & 63;
    if (row >= BATCH) return;

    u64 a = Ap[(size_t)row * 64 + lane];
    unsigned p[NOUT];
    #pragma unroll
    for (int j = 0; j < NOUT; ++j)
        p[j] = (unsigned)__popcll(a ^ Wp[j * 64 + lane]);

    #pragma unroll
    for (int j = 0; j < NOUT; ++j) {
        #pragma unroll
        for (int off = 32; off >= 1; off >>= 1)
            p[j] += __shfl_xor(p[j], off, 64);
    }

    float z[NOUT];
    float mx = -1e30f;
    #pragma unroll
    for (int j = 0; j < NOUT; ++j) {
        float h  = (float)(HID - 2 * (int)p[j]) + bias[j];
        float sc = gam[j] * rsqrtf(var[j] + EPS);
        z[j] = (h - mu[j]) * sc + bet[j];
        mx = fmaxf(mx, z[j]);
    }
    float s = 0.0f;
    #pragma unroll
    for (int j = 0; j < NOUT; ++j) s += expf(z[j] - mx);
    float lse = logf(s) + mx;
    if (lane < NOUT) out[(size_t)row * NOUT + lane] = z[lane] - lse;
}

// ---------------------------------------------------------------------------
extern "C" void kernel_launch(void* const* d_in, const int* in_sizes, int n_in,
                              void* d_out, int out_size, void* d_ws, size_t ws_size,
                              hipStream_t stream) {
    (void)in_sizes; (void)n_in; (void)out_size; (void)ws_size;

    const float* x   = (const float*)d_in[0];
    const float* w1  = (const float*)d_in[1];
    const float* b1  = (const float*)d_in[2];
    const float* g1  = (const float*)d_in[3];
    const float* be1 = (const float*)d_in[4];
    const float* m1  = (const float*)d_in[5];
    const float* v1  = (const float*)d_in[6];
    const float* w2  = (const float*)d_in[7];
    const float* b2  = (const float*)d_in[8];
    const float* g2  = (const float*)d_in[9];
    const float* be2 = (const float*)d_in[10];
    const float* m2  = (const float*)d_in[11];
    const float* v2  = (const float*)d_in[12];
    const float* w3  = (const float*)d_in[13];
    const float* b3  = (const float*)d_in[14];
    const float* g3  = (const float*)d_in[15];
    const float* be3 = (const float*)d_in[16];
    const float* m3  = (const float*)d_in[17];
    const float* v3  = (const float*)d_in[18];
    const float* w4  = (const float*)d_in[19];
    const float* b4  = (const float*)d_in[20];
    const float* g4  = (const float*)d_in[21];
    const float* be4 = (const float*)d_in[22];
    const float* m4  = (const float*)d_in[23];
    const float* v4  = (const float*)d_in[24];

    u64* ws  = (u64*)d_ws;
    u64* xp  = ws;                             // 16384*12
    u64* w1p = xp  + (size_t)BATCH * 12;       // 4096*12
    u64* w2p = w1p + (size_t)HID * 12;         // 4096*64
    u64* w3p = w2p + (size_t)HID * 64;         // 4096*64
    u64* w4p = w3p + (size_t)HID * 64;         // 10*64
    u64* a1  = w4p + (size_t)NOUT * 64;        // 16384*64
    u64* a2  = a1  + (size_t)BATCH * 64;       // 16384*64
    u64* a3  = a2  + (size_t)BATCH * 64;       // 16384*64

    // pack inputs & weights (x: ld=784, use first 768 cols)
    pack_sign_kernel<<<BATCH / 4, 256, 0, stream>>>(x, 784, 12, BATCH, xp);
    pack_sign_kernel<<<HID / 4, 256, 0, stream>>>(w1, IND, 12, HID, w1p);
    pack_sign_kernel<<<HID / 4, 256, 0, stream>>>(w2, HID, 64, HID, w2p);
    pack_sign_kernel<<<HID / 4, 256, 0, stream>>>(w3, HID, 64, HID, w3p);
    pack_sign_kernel<<<3, 256, 0, stream>>>(w4, HID, 64, NOUT, w4p);

    // layers 1-3: binarized GEMM + BN + sign -> packed
    bgemm_bn_sign<12><<<4096, 256, 0, stream>>>(xp, 12, w1p, IND,
                                                b1, g1, be1, m1, v1, a1);
    bgemm_bn_sign<16><<<4096, 256, 0, stream>>>(a1, 64, w2p, HID,
                                                b2, g2, be2, m2, v2, a2);
    bgemm_bn_sign<16><<<4096, 256, 0, stream>>>(a2, 64, w3p, HID,
                                                b3, g3, be3, m3, v3, a3);
    // layer 4 + log_softmax
    final_layer_kernel<<<BATCH / 4, 256, 0, stream>>>(a3, w4p,
                                                      b4, g4, be4, m4, v4,
                                                      (float*)d_out);
}

// Round 4
// 1126.616 us; speedup vs baseline: 2.6859x; 2.6859x over previous
//
#include <hip/hip_runtime.h>
#include <stdint.h>

typedef unsigned long long u64;
typedef int v4i __attribute__((ext_vector_type(4)));

#define BATCH 16384
#define IND   768
#define HID   4096
#define NOUT  10
#define EPS   1e-5f

// ---------------------------------------------------------------------------
// Pack sign bits: bit=1  <=>  value < 0.  One wave per row, ballot per 64 cols.
// ---------------------------------------------------------------------------
__global__ void pack_sign_kernel(const float* __restrict__ src, int ld, int nwords,
                                 int nrows, u64* __restrict__ dst) {
    int gt   = blockIdx.x * blockDim.x + threadIdx.x;
    int wave = gt >> 6;
    int lane = gt & 63;
    if (wave >= nrows) return;
    const float* row = src + (size_t)wave * ld;
    u64* drow = dst + (size_t)wave * nwords;
    for (int w = 0; w < nwords; ++w) {
        float v = row[(w << 6) + lane];
        u64 m = __ballot(v < 0.0f);
        if (lane == 0) drow[w] = m;
    }
}

// ---------------------------------------------------------------------------
// Row popcount over kw packed words (kw <= 64). One wave per row.
// ---------------------------------------------------------------------------
__global__ void rowpop_kernel(const u64* __restrict__ p, int kw, int rows,
                              int* __restrict__ out) {
    int gt   = blockIdx.x * blockDim.x + threadIdx.x;
    int row  = gt >> 6;
    int lane = gt & 63;
    if (row >= rows) return;
    int s = (lane < kw) ? (int)__popcll(p[(size_t)row * kw + lane]) : 0;
    #pragma unroll
    for (int off = 32; off >= 1; off >>= 1) s += __shfl_xor(s, off, 64);
    if (lane == 0) out[row] = s;
}

// ---------------------------------------------------------------------------
// Expand packed W bits -> swizzled 0/1 bytes for conflict-free LDS staging.
// Layout: tile per (nblock=row>>7, chunk c): 128 rows x 80 B (64 data + 16 pad).
// N*2 threads; thread (r,h) writes 32 B per chunk.
// ---------------------------------------------------------------------------
__global__ void expand_w_kernel(const u64* __restrict__ Wp, int kw,
                                signed char* __restrict__ Wsw) {
    int gt = blockIdx.x * blockDim.x + threadIdx.x;
    int r  = gt >> 1, h = gt & 1;
    const unsigned* wrow = (const unsigned*)(Wp + (size_t)r * kw);
    for (int c = 0; c < kw; ++c) {
        unsigned a32 = wrow[2 * c + h];
        unsigned o[8];
        #pragma unroll
        for (int k = 0; k < 8; ++k)
            o[k] = (((a32 >> (4 * k)) & 0xFu) * 0x00204081u) & 0x01010101u;
        uint4* dst = (uint4*)(Wsw + ((size_t)((r >> 7) * kw + c)) * 10240
                              + (r & 127) * 80 + h * 32);
        dst[0] = make_uint4(o[0], o[1], o[2], o[3]);
        dst[1] = make_uint4(o[4], o[5], o[6], o[7]);
    }
}

// ---------------------------------------------------------------------------
// Binarized GEMM via i8 MFMA on 0/1 bytes + popcount correction + BN + sign.
// dot_pm = kfull - 2*Pa[m] - 2*Pw[n] + 4*acc;  y = (dot+bias-mu)*scale+beta
// Block 128x128, 256 thr (4 waves, 2x2 quadrants of 64x64), BK=64 bits/chunk.
// A: packed bits expanded in-kernel (nibble-spread). B: verbatim copy of the
// pre-swizzled 0/1 byte tiles. acc in AGPRs via MFMA (no VALU churn).
// ---------------------------------------------------------------------------
__global__ __launch_bounds__(256, 3) void bgemm_i8(
    const u64* __restrict__ Ap, int kwA,       // packed A bits [M][kwA]
    const signed char* __restrict__ Wsw,       // swizzled 0/1 bytes
    const int* __restrict__ Pa, const int* __restrict__ Pw, int kfull,
    const float* __restrict__ bias, const float* __restrict__ gam,
    const float* __restrict__ bet,  const float* __restrict__ mu,
    const float* __restrict__ var,
    u64* __restrict__ Op)                      // out packed [M][64]
{
    __shared__ __align__(16) signed char A_lds[128 * 80];
    __shared__ __align__(16) signed char B_lds[128 * 80];
    __shared__ unsigned char smask[128 * 128];

    const int tid = threadIdx.x;
    const int bn  = blockIdx.x >> 7;           // 32 col blocks (major -> W reuse)
    const int bm  = blockIdx.x & 127;          // 128 row blocks
    const int m0  = bm << 7;
    const int n0  = bn << 7;

    const int wave = tid >> 6, lane = tid & 63;
    const int mh = (wave & 1) << 6, nh = (wave >> 1) << 6;
    const int l15 = lane & 15, lq = lane >> 4;

    v4i acc[4][4];
    #pragma unroll
    for (int i = 0; i < 4; ++i)
        #pragma unroll
        for (int j = 0; j < 4; ++j) acc[i][j] = (v4i){0, 0, 0, 0};

    const int r = tid >> 1, h = tid & 1;
    const unsigned* arow = (const unsigned*)(Ap + (size_t)(m0 + r) * kwA);
    signed char* adst = A_lds + r * 80 + h * 32;
    const signed char* pAf = A_lds + (mh + l15) * 80 + lq * 16;
    const signed char* pBf = B_lds + (nh + l15) * 80 + lq * 16;

    for (int c = 0; c < kwA; ++c) {
        // fetch staging data into registers (no LDS touch yet)
        unsigned a32 = arow[2 * c + h];
        const uint2* bsrc = (const uint2*)(Wsw + (size_t)(bn * kwA + c) * 10240);
        uint2 bv[5];
        #pragma unroll
        for (int k = 0; k < 5; ++k) bv[k] = bsrc[tid + (k << 8)];

        unsigned o[8];
        #pragma unroll
        for (int k = 0; k < 8; ++k)
            o[k] = (((a32 >> (4 * k)) & 0xFu) * 0x00204081u) & 0x01010101u;

        __syncthreads();                        // prev chunk's frag reads done
        ((uint4*)adst)[0] = make_uint4(o[0], o[1], o[2], o[3]);
        ((uint4*)adst)[1] = make_uint4(o[4], o[5], o[6], o[7]);
        uint2* bdst = (uint2*)B_lds;
        #pragma unroll
        for (int k = 0; k < 5; ++k) bdst[tid + (k << 8)] = bv[k];
        __syncthreads();                        // staging visible

        v4i af[4], bf[4];
        #pragma unroll
        for (int t = 0; t < 4; ++t) {
            af[t] = *(const v4i*)(pAf + t * 16 * 80);
            bf[t] = *(const v4i*)(pBf + t * 16 * 80);
        }
        #pragma unroll
        for (int i = 0; i < 4; ++i)
            #pragma unroll
            for (int j = 0; j < 4; ++j)
                acc[i][j] = __builtin_amdgcn_mfma_i32_16x16x64_i8(
                    af[i], bf[j], acc[i][j], 0, 0, 0);
    }

    // epilogue: BN sign bits into LDS byte mask
    float scj[4], basej[4], bej[4];
    #pragma unroll
    for (int j = 0; j < 4; ++j) {
        int n = n0 + nh + j * 16 + l15;
        scj[j]   = gam[n] * rsqrtf(var[n] + EPS);
        basej[j] = (float)(kfull - 2 * Pw[n]) + bias[n] - mu[n];
        bej[j]   = bet[n];
    }
    #pragma unroll
    for (int i = 0; i < 4; ++i) {
        #pragma unroll
        for (int r4 = 0; r4 < 4; ++r4) {
            int mloc = mh + i * 16 + lq * 4 + r4;
            float rowoff = -2.0f * (float)Pa[m0 + mloc];
            #pragma unroll
            for (int j = 0; j < 4; ++j) {
                float y = (basej[j] + rowoff + 4.0f * (float)acc[i][j][r4]) * scj[j]
                          + bej[j];
                smask[(mloc << 7) + nh + j * 16 + l15] = (y < 0.0f) ? 1 : 0;
            }
        }
    }
    __syncthreads();

    // pack 64 sign bytes -> one u64 per (row, half); 256 threads = 128 rows x 2
    {
        const u64* q = (const u64*)&smask[(r << 7) + (h << 6)];
        u64 word = 0;
        #pragma unroll
        for (int t = 0; t < 8; ++t) {
            u64 bits8 = (q[t] * 0x0102040810204080ULL) >> 56;  // byte k -> bit k
            word |= bits8 << (t << 3);
        }
        Op[(size_t)(m0 + r) * 64 + (n0 >> 6) + h] = word;
    }
}

// ---------------------------------------------------------------------------
// Final layer: N=10, K=4096 words=64. One wave per row; wave-reduce 10 dots,
// BN, log_softmax, write 10 outputs.
// ---------------------------------------------------------------------------
__global__ void final_layer_kernel(
    const u64* __restrict__ Ap,   // [B][64]
    const u64* __restrict__ Wp,   // [10][64]
    const float* __restrict__ bias, const float* __restrict__ gam,
    const float* __restrict__ bet,  const float* __restrict__ mu,
    const float* __restrict__ var,
    float* __restrict__ out)      // [B][10]
{
    int gt   = blockIdx.x * blockDim.x + threadIdx.x;
    int row  = gt >> 6;
    int lane = gt & 63;
    if (row >= BATCH) return;

    u64 a = Ap[(size_t)row * 64 + lane];
    unsigned p[NOUT];
    #pragma unroll
    for (int j = 0; j < NOUT; ++j)
        p[j] = (unsigned)__popcll(a ^ Wp[j * 64 + lane]);

    #pragma unroll
    for (int j = 0; j < NOUT; ++j) {
        #pragma unroll
        for (int off = 32; off >= 1; off >>= 1)
            p[j] += __shfl_xor(p[j], off, 64);
    }

    float z[NOUT];
    float mx = -1e30f;
    #pragma unroll
    for (int j = 0; j < NOUT; ++j) {
        float hh = (float)(HID - 2 * (int)p[j]) + bias[j];
        float sc = gam[j] * rsqrtf(var[j] + EPS);
        z[j] = (hh - mu[j]) * sc + bet[j];
        mx = fmaxf(mx, z[j]);
    }
    float s = 0.0f;
    #pragma unroll
    for (int j = 0; j < NOUT; ++j) s += expf(z[j] - mx);
    float lse = logf(s) + mx;
    if (lane < NOUT) out[(size_t)row * NOUT + lane] = z[lane] - lse;
}

// ---------------------------------------------------------------------------
extern "C" void kernel_launch(void* const* d_in, const int* in_sizes, int n_in,
                              void* d_out, int out_size, void* d_ws, size_t ws_size,
                              hipStream_t stream) {
    (void)in_sizes; (void)n_in; (void)out_size; (void)ws_size;

    const float* x   = (const float*)d_in[0];
    const float* w1  = (const float*)d_in[1];
    const float* b1  = (const float*)d_in[2];
    const float* g1  = (const float*)d_in[3];
    const float* be1 = (const float*)d_in[4];
    const float* m1  = (const float*)d_in[5];
    const float* v1  = (const float*)d_in[6];
    const float* w2  = (const float*)d_in[7];
    const float* b2  = (const float*)d_in[8];
    const float* g2  = (const float*)d_in[9];
    const float* be2 = (const float*)d_in[10];
    const float* m2  = (const float*)d_in[11];
    const float* v2  = (const float*)d_in[12];
    const float* w3  = (const float*)d_in[13];
    const float* b3  = (const float*)d_in[14];
    const float* g3  = (const float*)d_in[15];
    const float* be3 = (const float*)d_in[16];
    const float* m3  = (const float*)d_in[17];
    const float* v3  = (const float*)d_in[18];
    const float* w4  = (const float*)d_in[19];
    const float* b4  = (const float*)d_in[20];
    const float* g4  = (const float*)d_in[21];
    const float* be4 = (const float*)d_in[22];
    const float* m4  = (const float*)d_in[23];
    const float* v4  = (const float*)d_in[24];

    u64* ws  = (u64*)d_ws;
    u64* xp  = ws;                             // 16384*12
    u64* w1p = xp  + (size_t)BATCH * 12;       // 4096*12
    u64* w2p = w1p + (size_t)HID * 12;         // 4096*64
    u64* w3p = w2p + (size_t)HID * 64;         // 4096*64
    u64* w4p = w3p + (size_t)HID * 64;         // 10*64
    u64* a1  = w4p + (size_t)NOUT * 64;        // 16384*64
    u64* a2  = a1  + (size_t)BATCH * 64;       // 16384*64
    u64* a3  = a2  + (size_t)BATCH * 64;       // 16384*64
    int* Pa  = (int*)(a3 + (size_t)BATCH * 64);      // 16384 ints
    int* Pw  = Pa + BATCH;                           // 4096 ints
    signed char* Wsw = (signed char*)(Pw + HID);     // 32*64*10240 = 21 MB

    // pack inputs & weights (x: ld=784, use first 768 cols)
    pack_sign_kernel<<<BATCH / 4, 256, 0, stream>>>(x, 784, 12, BATCH, xp);
    pack_sign_kernel<<<HID / 4, 256, 0, stream>>>(w1, IND, 12, HID, w1p);
    pack_sign_kernel<<<HID / 4, 256, 0, stream>>>(w2, HID, 64, HID, w2p);
    pack_sign_kernel<<<HID / 4, 256, 0, stream>>>(w3, HID, 64, HID, w3p);
    pack_sign_kernel<<<3, 256, 0, stream>>>(w4, HID, 64, NOUT, w4p);

    // layer 1 (K=768, 12 chunks)
    rowpop_kernel<<<BATCH / 4, 256, 0, stream>>>(xp, 12, BATCH, Pa);
    rowpop_kernel<<<HID / 4, 256, 0, stream>>>(w1p, 12, HID, Pw);
    expand_w_kernel<<<(HID * 2) / 256, 256, 0, stream>>>(w1p, 12, Wsw);
    bgemm_i8<<<4096, 256, 0, stream>>>(xp, 12, Wsw, Pa, Pw, IND,
                                       b1, g1, be1, m1, v1, a1);
    // layer 2 (K=4096, 64 chunks)
    rowpop_kernel<<<BATCH / 4, 256, 0, stream>>>(a1, 64, BATCH, Pa);
    rowpop_kernel<<<HID / 4, 256, 0, stream>>>(w2p, 64, HID, Pw);
    expand_w_kernel<<<(HID * 2) / 256, 256, 0, stream>>>(w2p, 64, Wsw);
    bgemm_i8<<<4096, 256, 0, stream>>>(a1, 64, Wsw, Pa, Pw, HID,
                                       b2, g2, be2, m2, v2, a2);
    // layer 3
    rowpop_kernel<<<BATCH / 4, 256, 0, stream>>>(a2, 64, BATCH, Pa);
    rowpop_kernel<<<HID / 4, 256, 0, stream>>>(w3p, 64, HID, Pw);
    expand_w_kernel<<<(HID * 2) / 256, 256, 0, stream>>>(w3p, 64, Wsw);
    bgemm_i8<<<4096, 256, 0, stream>>>(a2, 64, Wsw, Pa, Pw, HID,
                                       b3, g3, be3, m3, v3, a3);
    // layer 4 + log_softmax
    final_layer_kernel<<<BATCH / 4, 256, 0, stream>>>(a3, w4p,
                                                      b4, g4, be4, m4, v4,
                                                      (float*)d_out);
}

// Round 5
// 920.504 us; speedup vs baseline: 3.2873x; 1.2239x over previous
//
#include <hip/hip_runtime.h>
#include <stdint.h>

typedef unsigned long long u64;
typedef int v4i  __attribute__((ext_vector_type(4)));
typedef int v16i __attribute__((ext_vector_type(16)));

#define BATCH 16384
#define IND   768
#define HID   4096
#define NOUT  10
#define EPS   1e-5f

// ---------------------------------------------------------------------------
// Pack sign bits row-major: dst[row][w]. Used for W4 only (final layer).
// ---------------------------------------------------------------------------
__global__ void pack_sign_kernel(const float* __restrict__ src, int ld, int nwords,
                                 int nrows, u64* __restrict__ dst) {
    int gt   = blockIdx.x * blockDim.x + threadIdx.x;
    int wave = gt >> 6;
    int lane = gt & 63;
    if (wave >= nrows) return;
    const float* row = src + (size_t)wave * ld;
    u64* drow = dst + (size_t)wave * nwords;
    for (int w = 0; w < nwords; ++w) {
        float v = row[(w << 6) + lane];
        u64 m = __ballot(v < 0.0f);
        if (lane == 0) drow[w] = m;
    }
}

// ---------------------------------------------------------------------------
// Pack sign bits TRANSPOSED: dst[w][row] (plane stride = nrows). Coalesced
// staging loads in the GEMM. bit=1 <=> value < 0.
// ---------------------------------------------------------------------------
__global__ void pack_sign_t_kernel(const float* __restrict__ src, int ld,
                                   int nwords, int nrows, u64* __restrict__ dst) {
    int gt   = blockIdx.x * blockDim.x + threadIdx.x;
    int row  = gt >> 6;
    int lane = gt & 63;
    if (row >= nrows) return;
    const float* r = src + (size_t)row * ld;
    for (int w = 0; w < nwords; ++w) {
        float v = r[(w << 6) + lane];
        u64 m = __ballot(v < 0.0f);
        if (lane == 0) dst[(size_t)w * nrows + row] = m;
    }
}

// ---------------------------------------------------------------------------
// 16 bits -> 16 bytes of 0/1 (v4i), byte j = bit j.
// ---------------------------------------------------------------------------
__device__ __forceinline__ v4i expand16(unsigned b) {
    v4i r;
    r[0] = (int)((( b        & 0xFu) * 0x00204081u) & 0x01010101u);
    r[1] = (int)((((b >> 4)  & 0xFu) * 0x00204081u) & 0x01010101u);
    r[2] = (int)((((b >> 8)  & 0xFu) * 0x00204081u) & 0x01010101u);
    r[3] = (int)((((b >> 12) & 0xFu) * 0x00204081u) & 0x01010101u);
    return r;
}

// ---------------------------------------------------------------------------
// Binarized GEMM: bits staged in LDS (2KB/round), expanded to 0/1 bytes in
// registers, mfma_i32_32x32x32_i8. dot = kfull - 2Pa - 2Pw + 4*acc (exact int).
// Block 128x128, 4 waves in 2x2 quadrants of 64x64 (2x2 mfma of 32x32 each).
// Row popcounts (Pa/Pw) accumulated during staging. Sign-pack via ballot.
// Output transposed OT[plane][row]; optional row-major copy ORM for the
// final layer.
// ---------------------------------------------------------------------------
__global__ __launch_bounds__(256, 3) void bgemm_i8t(
    const u64* __restrict__ AT,   // [kw][BATCH] bit planes
    int kw, int kfull,
    const u64* __restrict__ WT,   // [kw][HID] bit planes
    const float* __restrict__ bias, const float* __restrict__ gam,
    const float* __restrict__ bet,  const float* __restrict__ mu,
    const float* __restrict__ var,
    u64* __restrict__ OT,         // [64][BATCH]
    u64* __restrict__ ORM)        // [BATCH][64] or nullptr
{
    __shared__ u64 Apk[2 * 128];
    __shared__ u64 Bpk[2 * 128];
    __shared__ int paLDS[128];
    __shared__ int pwLDS[128];

    const int tid = threadIdx.x;
    const int bn  = blockIdx.x >> 7;        // B-major: 128 blocks share W slab
    const int bm  = blockIdx.x & 127;
    const int m0  = bm << 7, n0 = bn << 7;

    const int wave = tid >> 6, lane = tid & 63;
    const int mh = (wave & 1) << 6, nh = (wave >> 1) << 6;
    const int l31 = lane & 31, q = lane >> 5;

    v16i acc[2][2];
    #pragma unroll
    for (int a = 0; a < 2; ++a)
        #pragma unroll
        for (int b = 0; b < 2; ++b)
            #pragma unroll
            for (int k = 0; k < 16; ++k) acc[a][b][k] = 0;

    const bool isA = tid < 128;             // wave-uniform
    const int  sr  = isA ? tid : tid - 128;
    const u64* gbase   = isA ? (AT + m0 + sr) : (WT + n0 + sr);
    const int  gstride = isA ? BATCH : HID;

    int pacc = 0;
    const int rounds = kw >> 1;
    for (int c = 0; c < rounds; ++c) {
        u64 g0 = gbase[(size_t)(2 * c)     * gstride];
        u64 g1 = gbase[(size_t)(2 * c + 1) * gstride];
        pacc += (int)__popcll(g0) + (int)__popcll(g1);
        __syncthreads();                    // prev round's LDS reads done
        if (isA) { Apk[sr] = g0; Apk[128 + sr] = g1; }
        else     { Bpk[sr] = g0; Bpk[128 + sr] = g1; }
        __syncthreads();                    // staging visible

        u64 wa[2][2], wb[2][2];
        #pragma unroll
        for (int t = 0; t < 2; ++t)
            #pragma unroll
            for (int p = 0; p < 2; ++p) {
                wa[t][p] = Apk[p * 128 + mh + 32 * t + l31];
                wb[t][p] = Bpk[p * 128 + nh + 32 * t + l31];
            }

        v4i af[2][2][2], bf[2][2][2];       // [t][p][h]
        #pragma unroll
        for (int t = 0; t < 2; ++t)
            #pragma unroll
            for (int p = 0; p < 2; ++p) {
                u64 sa = wa[t][p] >> (16 * q);
                af[t][p][0] = expand16((unsigned)sa & 0xFFFFu);
                af[t][p][1] = expand16((unsigned)(sa >> 32) & 0xFFFFu);
                u64 sb = wb[t][p] >> (16 * q);
                bf[t][p][0] = expand16((unsigned)sb & 0xFFFFu);
                bf[t][p][1] = expand16((unsigned)(sb >> 32) & 0xFFFFu);
            }

        #pragma unroll
        for (int p = 0; p < 2; ++p)
            #pragma unroll
            for (int h = 0; h < 2; ++h)
                #pragma unroll
                for (int ti = 0; ti < 2; ++ti)
                    #pragma unroll
                    for (int tj = 0; tj < 2; ++tj)
                        acc[ti][tj] = __builtin_amdgcn_mfma_i32_32x32x32_i8(
                            af[ti][p][h], bf[tj][p][h], acc[ti][tj], 0, 0, 0);
    }

    // share row/col popcounts
    __syncthreads();
    if (isA) paLDS[sr] = pacc; else pwLDS[sr] = pacc;
    __syncthreads();

    // epilogue: exact-int dot, reference-order BN, ballot sign-pack
    float scj[2], muj[2], bej[2], bij[2];
    int pwj[2];
    #pragma unroll
    for (int tj = 0; tj < 2; ++tj) {
        int col = n0 + nh + 32 * tj + l31;
        scj[tj] = gam[col] * rsqrtf(var[col] + EPS);
        muj[tj] = mu[col]; bej[tj] = bet[col]; bij[tj] = bias[col];
        pwj[tj] = pwLDS[nh + 32 * tj + l31];
    }
    const int pn = (n0 + nh) >> 6;          // output bit-plane
    u64* outp = OT + (size_t)pn * BATCH;

    #pragma unroll
    for (int ti = 0; ti < 2; ++ti) {
        #pragma unroll
        for (int reg = 0; reg < 16; ++reg) {
            int rbase = (reg & 3) + 8 * (reg >> 2);
            int mloc  = mh + 32 * ti + rbase + 4 * q;   // this lane's row
            int pa    = paLDS[mloc];
            u64 bl[2];
            #pragma unroll
            for (int tj = 0; tj < 2; ++tj) {
                int idot = kfull - 2 * (pa + pwj[tj]) + 4 * acc[ti][tj][reg];
                float h  = (float)idot + bij[tj];
                float y  = (h - muj[tj]) * scj[tj] + bej[tj];
                bl[tj] = __ballot(y < 0.0f);
            }
            u64 rowA = (bl[0] & 0xFFFFFFFFull) | (bl[1] << 32);          // q=0 row
            u64 rowB = (bl[0] >> 32) | (bl[1] & 0xFFFFFFFF00000000ull);  // q=1 row
            int rA = mh + 32 * ti + rbase;
            if (lane == 0)       outp[m0 + rA]     = rowA;
            else if (lane == 32) outp[m0 + rA + 4] = rowB;
            if (ORM) {
                if (lane == 0)       ORM[(size_t)(m0 + rA)     * 64 + pn] = rowA;
                else if (lane == 32) ORM[(size_t)(m0 + rA + 4) * 64 + pn] = rowB;
            }
        }
    }
}

// ---------------------------------------------------------------------------
// Final layer: N=10, K=4096 (64 words). One wave per row; exact-int dots,
// BN, log_softmax.
// ---------------------------------------------------------------------------
__global__ void final_layer_kernel(
    const u64* __restrict__ Ap,   // [B][64] row-major
    const u64* __restrict__ Wp,   // [10][64] row-major
    const float* __restrict__ bias, const float* __restrict__ gam,
    const float* __restrict__ bet,  const float* __restrict__ mu,
    const float* __restrict__ var,
    float* __restrict__ out)      // [B][10]
{
    int gt   = blockIdx.x * blockDim.x + threadIdx.x;
    int row  = gt >> 6;
    int lane = gt & 63;
    if (row >= BATCH) return;

    u64 a = Ap[(size_t)row * 64 + lane];
    unsigned p[NOUT];
    #pragma unroll
    for (int j = 0; j < NOUT; ++j)
        p[j] = (unsigned)__popcll(a ^ Wp[j * 64 + lane]);

    #pragma unroll
    for (int j = 0; j < NOUT; ++j) {
        #pragma unroll
        for (int off = 32; off >= 1; off >>= 1)
            p[j] += __shfl_xor(p[j], off, 64);
    }

    float z[NOUT];
    float mx = -1e30f;
    #pragma unroll
    for (int j = 0; j < NOUT; ++j) {
        float hh = (float)(HID - 2 * (int)p[j]) + bias[j];
        float sc = gam[j] * rsqrtf(var[j] + EPS);
        z[j] = (hh - mu[j]) * sc + bet[j];
        mx = fmaxf(mx, z[j]);
    }
    float s = 0.0f;
    #pragma unroll
    for (int j = 0; j < NOUT; ++j) s += expf(z[j] - mx);
    float lse = logf(s) + mx;
    if (lane < NOUT) out[(size_t)row * NOUT + lane] = z[lane] - lse;
}

// ---------------------------------------------------------------------------
extern "C" void kernel_launch(void* const* d_in, const int* in_sizes, int n_in,
                              void* d_out, int out_size, void* d_ws, size_t ws_size,
                              hipStream_t stream) {
    (void)in_sizes; (void)n_in; (void)out_size; (void)ws_size;

    const float* x   = (const float*)d_in[0];
    const float* w1  = (const float*)d_in[1];
    const float* b1  = (const float*)d_in[2];
    const float* g1  = (const float*)d_in[3];
    const float* be1 = (const float*)d_in[4];
    const float* m1  = (const float*)d_in[5];
    const float* v1  = (const float*)d_in[6];
    const float* w2  = (const float*)d_in[7];
    const float* b2  = (const float*)d_in[8];
    const float* g2  = (const float*)d_in[9];
    const float* be2 = (const float*)d_in[10];
    const float* m2  = (const float*)d_in[11];
    const float* v2  = (const float*)d_in[12];
    const float* w3  = (const float*)d_in[13];
    const float* b3  = (const float*)d_in[14];
    const float* g3  = (const float*)d_in[15];
    const float* be3 = (const float*)d_in[16];
    const float* m3  = (const float*)d_in[17];
    const float* v3  = (const float*)d_in[18];
    const float* w4  = (const float*)d_in[19];
    const float* b4  = (const float*)d_in[20];
    const float* g4  = (const float*)d_in[21];
    const float* be4 = (const float*)d_in[22];
    const float* m4  = (const float*)d_in[23];
    const float* v4  = (const float*)d_in[24];

    u64* ws   = (u64*)d_ws;
    u64* xpT  = ws;                              // 12*16384
    u64* w1T  = xpT + (size_t)12 * BATCH;        // 12*4096
    u64* w2T  = w1T + (size_t)12 * HID;          // 64*4096
    u64* w3T  = w2T + (size_t)64 * HID;          // 64*4096
    u64* w4p  = w3T + (size_t)64 * HID;          // 10*64
    u64* a1T  = w4p + (size_t)NOUT * 64;         // 64*16384
    u64* a2T  = a1T + (size_t)64 * BATCH;        // 64*16384
    u64* a3RM = a2T + (size_t)64 * BATCH;        // 16384*64
    u64* a3T  = a1T;                             // reuse (a1 dead in layer 3)

    // pack (transposed bit-planes; w4 row-major for the final kernel)
    pack_sign_t_kernel<<<BATCH / 4, 256, 0, stream>>>(x, 784, 12, BATCH, xpT);
    pack_sign_t_kernel<<<HID / 4, 256, 0, stream>>>(w1, IND, 12, HID, w1T);
    pack_sign_t_kernel<<<HID / 4, 256, 0, stream>>>(w2, HID, 64, HID, w2T);
    pack_sign_t_kernel<<<HID / 4, 256, 0, stream>>>(w3, HID, 64, HID, w3T);
    pack_sign_kernel<<<3, 256, 0, stream>>>(w4, HID, 64, NOUT, w4p);

    // layers 1-3
    bgemm_i8t<<<4096, 256, 0, stream>>>(xpT, 12, IND, w1T,
                                        b1, g1, be1, m1, v1, a1T, nullptr);
    bgemm_i8t<<<4096, 256, 0, stream>>>(a1T, 64, HID, w2T,
                                        b2, g2, be2, m2, v2, a2T, nullptr);
    bgemm_i8t<<<4096, 256, 0, stream>>>(a2T, 64, HID, w3T,
                                        b3, g3, be3, m3, v3, a3T, a3RM);
    // layer 4 + log_softmax
    final_layer_kernel<<<BATCH / 4, 256, 0, stream>>>(a3RM, w4p,
                                                      b4, g4, be4, m4, v4,
                                                      (float*)d_out);
}

// Round 6
// 919.008 us; speedup vs baseline: 3.2926x; 1.0016x over previous
//
#include <hip/hip_runtime.h>
#include <stdint.h>

typedef unsigned long long u64;
typedef int v4i  __attribute__((ext_vector_type(4)));
typedef int v16i __attribute__((ext_vector_type(16)));

#define BATCH 16384
#define IND   768
#define HID   4096
#define NOUT  10
#define EPS   1e-5f

// ---------------------------------------------------------------------------
// Pack sign bits row-major: dst[row][w]. Used for W4 only (final layer).
// ---------------------------------------------------------------------------
__global__ void pack_sign_kernel(const float* __restrict__ src, int ld, int nwords,
                                 int nrows, u64* __restrict__ dst) {
    int gt   = blockIdx.x * blockDim.x + threadIdx.x;
    int wave = gt >> 6;
    int lane = gt & 63;
    if (wave >= nrows) return;
    const float* row = src + (size_t)wave * ld;
    u64* drow = dst + (size_t)wave * nwords;
    for (int w = 0; w < nwords; ++w) {
        float v = row[(w << 6) + lane];
        u64 m = __ballot(v < 0.0f);
        if (lane == 0) drow[w] = m;
    }
}

// ---------------------------------------------------------------------------
// Pack sign bits TRANSPOSED: dst[w][row]. One block per row, 4 waves split
// the word range (shorter ballot chains, 4x parallelism vs R5 version).
// ---------------------------------------------------------------------------
__global__ void pack_sign_t_kernel(const float* __restrict__ src, int ld,
                                   int nwords, int nrows, u64* __restrict__ dst) {
    int row  = blockIdx.x;
    int wave = threadIdx.x >> 6, lane = threadIdx.x & 63;
    int nw4  = (nwords + 3) >> 2;
    int wend = (wave + 1) * nw4; if (wend > nwords) wend = nwords;
    const float* r = src + (size_t)row * ld;
    for (int w = wave * nw4; w < wend; ++w) {
        u64 m = __ballot(r[(w << 6) + lane] < 0.0f);
        if (lane == 0) dst[(size_t)w * nrows + row] = m;
    }
}

// ---------------------------------------------------------------------------
// 16 bits -> 16 bytes of 0/1 (v4i), byte j = bit j.
// ---------------------------------------------------------------------------
__device__ __forceinline__ v4i expand16(unsigned b) {
    v4i r;
    r[0] = (int)((( b        & 0xFu) * 0x00204081u) & 0x01010101u);
    r[1] = (int)((((b >> 4)  & 0xFu) * 0x00204081u) & 0x01010101u);
    r[2] = (int)((((b >> 8)  & 0xFu) * 0x00204081u) & 0x01010101u);
    r[3] = (int)((((b >> 12) & 0xFu) * 0x00204081u) & 0x01010101u);
    return r;
}

// ---------------------------------------------------------------------------
// Binarized GEMM, LDS-free K-loop: bit-words loaded straight from global
// (L2-resident: W bits = 2 MB total, A slab = 64 KB shared by the 32
// consecutive blocks of a bm-group), expanded to 0/1 bytes in registers,
// mfma_i32_32x32x32_i8. dot = kfull - 2Pa - 2Pw + 4*acc (exact int).
// No barriers in the K-loop -> compiler can pipeline loads across rounds.
// Row/col popcounts accumulated inline; one LDS exchange before epilogue.
// ---------------------------------------------------------------------------
__global__ __launch_bounds__(256, 3) void bgemm_i8g(
    const u64* __restrict__ AT,   // [kw][BATCH] bit planes
    int kw, int kfull,
    const u64* __restrict__ WT,   // [kw][HID] bit planes
    const float* __restrict__ bias, const float* __restrict__ gam,
    const float* __restrict__ bet,  const float* __restrict__ mu,
    const float* __restrict__ var,
    u64* __restrict__ OT,         // [64][BATCH]
    u64* __restrict__ ORM)        // [BATCH][64] or nullptr
{
    __shared__ int paLDS[128];
    __shared__ int pwLDS[128];

    const int tid = threadIdx.x;
    const int bm  = blockIdx.x >> 5;        // 32 consecutive blocks share A slab
    const int bn  = blockIdx.x & 31;
    const int m0  = bm << 7, n0 = bn << 7;

    const int wave = tid >> 6, lane = tid & 63;
    const int mh = (wave & 1) << 6, nh = (wave >> 1) << 6;
    const int l31 = lane & 31, q = lane >> 5;

    v16i acc[2][2];
    #pragma unroll
    for (int a = 0; a < 2; ++a)
        #pragma unroll
        for (int b = 0; b < 2; ++b)
            #pragma unroll
            for (int k = 0; k < 16; ++k) acc[a][b][k] = 0;

    const u64* Abase = AT + m0 + mh + l31;  // + 32t + word*BATCH
    const u64* Wbase = WT + n0 + nh + l31;  // + 32t + word*HID

    int pa_t[2] = {0, 0}, pw_t[2] = {0, 0};

    const int rounds = kw >> 1;
    for (int c = 0; c < rounds; ++c) {
        u64 wa[2][2], wb[2][2];
        #pragma unroll
        for (int p = 0; p < 2; ++p) {
            size_t ko = (size_t)(2 * c + p);
            #pragma unroll
            for (int t = 0; t < 2; ++t) {
                wa[t][p] = Abase[ko * BATCH + 32 * t];
                wb[t][p] = Wbase[ko * HID  + 32 * t];
            }
        }
        #pragma unroll
        for (int t = 0; t < 2; ++t) {
            pa_t[t] += (int)__popcll(wa[t][0]) + (int)__popcll(wa[t][1]);
            pw_t[t] += (int)__popcll(wb[t][0]) + (int)__popcll(wb[t][1]);
        }

        v4i af[2][2][2], bf[2][2][2];       // [t][p][h]
        #pragma unroll
        for (int t = 0; t < 2; ++t)
            #pragma unroll
            for (int p = 0; p < 2; ++p) {
                u64 sa = wa[t][p] >> (16 * q);
                af[t][p][0] = expand16((unsigned)sa & 0xFFFFu);
                af[t][p][1] = expand16((unsigned)(sa >> 32) & 0xFFFFu);
                u64 sb = wb[t][p] >> (16 * q);
                bf[t][p][0] = expand16((unsigned)sb & 0xFFFFu);
                bf[t][p][1] = expand16((unsigned)(sb >> 32) & 0xFFFFu);
            }

        #pragma unroll
        for (int p = 0; p < 2; ++p)
            #pragma unroll
            for (int h = 0; h < 2; ++h)
                #pragma unroll
                for (int ti = 0; ti < 2; ++ti)
                    #pragma unroll
                    for (int tj = 0; tj < 2; ++tj)
                        acc[ti][tj] = __builtin_amdgcn_mfma_i32_32x32x32_i8(
                            af[ti][p][h], bf[tj][p][h], acc[ti][tj], 0, 0, 0);
    }

    // share row/col popcounts (waves with same mh/nh write identical values)
    if (q == 0) {
        paLDS[mh + l31]      = pa_t[0];
        paLDS[mh + 32 + l31] = pa_t[1];
        pwLDS[nh + l31]      = pw_t[0];
        pwLDS[nh + 32 + l31] = pw_t[1];
    }
    __syncthreads();

    // epilogue: exact-int dot, reference-order BN, ballot sign-pack
    float scj[2], muj[2], bej[2], bij[2];
    int pwj[2];
    #pragma unroll
    for (int tj = 0; tj < 2; ++tj) {
        int col = n0 + nh + 32 * tj + l31;
        scj[tj] = gam[col] * rsqrtf(var[col] + EPS);
        muj[tj] = mu[col]; bej[tj] = bet[col]; bij[tj] = bias[col];
        pwj[tj] = pwLDS[nh + 32 * tj + l31];
    }
    const int pn = (n0 + nh) >> 6;          // output bit-plane
    u64* outp = OT + (size_t)pn * BATCH;

    #pragma unroll
    for (int ti = 0; ti < 2; ++ti) {
        #pragma unroll
        for (int reg = 0; reg < 16; ++reg) {
            int rbase = (reg & 3) + 8 * (reg >> 2);
            int mloc  = mh + 32 * ti + rbase + 4 * q;   // this lane's row
            int pa    = paLDS[mloc];
            u64 bl[2];
            #pragma unroll
            for (int tj = 0; tj < 2; ++tj) {
                int idot = kfull - 2 * (pa + pwj[tj]) + 4 * acc[ti][tj][reg];
                float h  = (float)idot + bij[tj];
                float y  = (h - muj[tj]) * scj[tj] + bej[tj];
                bl[tj] = __ballot(y < 0.0f);
            }
            u64 rowA = (bl[0] & 0xFFFFFFFFull) | (bl[1] << 32);          // q=0 row
            u64 rowB = (bl[0] >> 32) | (bl[1] & 0xFFFFFFFF00000000ull);  // q=1 row
            int rA = mh + 32 * ti + rbase;
            if (lane == 0)       outp[m0 + rA]     = rowA;
            else if (lane == 32) outp[m0 + rA + 4] = rowB;
            if (ORM) {
                if (lane == 0)       ORM[(size_t)(m0 + rA)     * 64 + pn] = rowA;
                else if (lane == 32) ORM[(size_t)(m0 + rA + 4) * 64 + pn] = rowB;
            }
        }
    }
}

// ---------------------------------------------------------------------------
// Final layer: N=10, K=4096 (64 words). One wave per row; exact-int dots,
// BN, log_softmax.
// ---------------------------------------------------------------------------
__global__ void final_layer_kernel(
    const u64* __restrict__ Ap,   // [B][64] row-major
    const u64* __restrict__ Wp,   // [10][64] row-major
    const float* __restrict__ bias, const float* __restrict__ gam,
    const float* __restrict__ bet,  const float* __restrict__ mu,
    const float* __restrict__ var,
    float* __restrict__ out)      // [B][10]
{
    int gt   = blockIdx.x * blockDim.x + threadIdx.x;
    int row  = gt >> 6;
    int lane = gt & 63;
    if (row >= BATCH) return;

    u64 a = Ap[(size_t)row * 64 + lane];
    unsigned p[NOUT];
    #pragma unroll
    for (int j = 0; j < NOUT; ++j)
        p[j] = (unsigned)__popcll(a ^ Wp[j * 64 + lane]);

    #pragma unroll
    for (int j = 0; j < NOUT; ++j) {
        #pragma unroll
        for (int off = 32; off >= 1; off >>= 1)
            p[j] += __shfl_xor(p[j], off, 64);
    }

    float z[NOUT];
    float mx = -1e30f;
    #pragma unroll
    for (int j = 0; j < NOUT; ++j) {
        float hh = (float)(HID - 2 * (int)p[j]) + bias[j];
        float sc = gam[j] * rsqrtf(var[j] + EPS);
        z[j] = (hh - mu[j]) * sc + bet[j];
        mx = fmaxf(mx, z[j]);
    }
    float s = 0.0f;
    #pragma unroll
    for (int j = 0; j < NOUT; ++j) s += expf(z[j] - mx);
    float lse = logf(s) + mx;
    if (lane < NOUT) out[(size_t)row * NOUT + lane] = z[lane] - lse;
}

// ---------------------------------------------------------------------------
extern "C" void kernel_launch(void* const* d_in, const int* in_sizes, int n_in,
                              void* d_out, int out_size, void* d_ws, size_t ws_size,
                              hipStream_t stream) {
    (void)in_sizes; (void)n_in; (void)out_size; (void)ws_size;

    const float* x   = (const float*)d_in[0];
    const float* w1  = (const float*)d_in[1];
    const float* b1  = (const float*)d_in[2];
    const float* g1  = (const float*)d_in[3];
    const float* be1 = (const float*)d_in[4];
    const float* m1  = (const float*)d_in[5];
    const float* v1  = (const float*)d_in[6];
    const float* w2  = (const float*)d_in[7];
    const float* b2  = (const float*)d_in[8];
    const float* g2  = (const float*)d_in[9];
    const float* be2 = (const float*)d_in[10];
    const float* m2  = (const float*)d_in[11];
    const float* v2  = (const float*)d_in[12];
    const float* w3  = (const float*)d_in[13];
    const float* b3  = (const float*)d_in[14];
    const float* g3  = (const float*)d_in[15];
    const float* be3 = (const float*)d_in[16];
    const float* m3  = (const float*)d_in[17];
    const float* v3  = (const float*)d_in[18];
    const float* w4  = (const float*)d_in[19];
    const float* b4  = (const float*)d_in[20];
    const float* g4  = (const float*)d_in[21];
    const float* be4 = (const float*)d_in[22];
    const float* m4  = (const float*)d_in[23];
    const float* v4  = (const float*)d_in[24];

    u64* ws   = (u64*)d_ws;
    u64* xpT  = ws;                              // 12*16384
    u64* w1T  = xpT + (size_t)12 * BATCH;        // 12*4096
    u64* w2T  = w1T + (size_t)12 * HID;          // 64*4096
    u64* w3T  = w2T + (size_t)64 * HID;          // 64*4096
    u64* w4p  = w3T + (size_t)64 * HID;          // 10*64
    u64* a1T  = w4p + (size_t)NOUT * 64;         // 64*16384
    u64* a2T  = a1T + (size_t)64 * BATCH;        // 64*16384
    u64* a3RM = a2T + (size_t)64 * BATCH;        // 16384*64
    u64* a3T  = a1T;                             // reuse (a1 dead in layer 3)

    // pack (transposed bit-planes; w4 row-major for the final kernel)
    pack_sign_t_kernel<<<BATCH, 256, 0, stream>>>(x, 784, 12, BATCH, xpT);
    pack_sign_t_kernel<<<HID, 256, 0, stream>>>(w1, IND, 12, HID, w1T);
    pack_sign_t_kernel<<<HID, 256, 0, stream>>>(w2, HID, 64, HID, w2T);
    pack_sign_t_kernel<<<HID, 256, 0, stream>>>(w3, HID, 64, HID, w3T);
    pack_sign_kernel<<<3, 256, 0, stream>>>(w4, HID, 64, NOUT, w4p);

    // layers 1-3
    bgemm_i8g<<<4096, 256, 0, stream>>>(xpT, 12, IND, w1T,
                                        b1, g1, be1, m1, v1, a1T, nullptr);
    bgemm_i8g<<<4096, 256, 0, stream>>>(a1T, 64, HID, w2T,
                                        b2, g2, be2, m2, v2, a2T, nullptr);
    bgemm_i8g<<<4096, 256, 0, stream>>>(a2T, 64, HID, w3T,
                                        b3, g3, be3, m3, v3, a3T, a3RM);
    // layer 4 + log_softmax
    final_layer_kernel<<<BATCH / 4, 256, 0, stream>>>(a3RM, w4p,
                                                      b4, g4, be4, m4, v4,
                                                      (float*)d_out);
}